// Round 4
// baseline (113.432 us; speedup 1.0000x reference)
//
#include <hip/hip_runtime.h>
#include <math.h>

// SANet attention: MFMA flash, global_load_lds-staged K/V (source-preswizzled),
// triple-buffered with COUNTED vmcnt (T3/T4), 32 q-rows/wave, split-K, f16
// partials. b=4, c=64, HW=4096, fp32 in/out.
//
// R8 post-mortem: occupancy 2->4 and LDS-traffic cuts were FLAT (attn ~44us
// across R6/R7/R8) -> wait-bound, not pipe-bound. The invariant was
// __syncthreads() per tile = s_waitcnt vmcnt(0) drain of the SAME-iteration
// prefetch, plus co-resident blocks (same (s,b)) missing HBM together.
// R9: triple-buffer Kl/Vl[3] (48KB, 3 blocks/CU, LB(256,3) -> cap 170 VGPR),
// per tile: s_waitcnt vmcnt(4) -> raw s_barrier -> stage(kt+2) -> compute.
// Prefetch gets 2 full tile-phases to land; never vmcnt(0) in the loop.
// Safety: each wave waits its own vmcnt before barrier => buffer kt valid for
// all; stage(kt+2) issued after barrier kt, target buffer last read kt-1.
// Fences: "memory" asm + sched_barrier(0) around raw barrier; fence between
// Q-gather loads and prologue stages keeps manual vmcnt counting exact.
//
// mfma_f32_16x16x32_f16: A[m=lane&15][k=quad*8+j], B[k=quad*8+j][n=lane&15],
// D[m=quad*4+reg][n=lane&15]  (quad = lane>>4).
// S-mfma computes S^T tile (m=k_key, n=q); PV computes O^T (m=c, n=q).
//
// P redistribution (verified R7): with A_m=pk(sv[m][0],sv[m][1]),
// B_m=pk(sv[m][2],sv[m][3]):  (w0,w2)=pl16swap(pl32swap(A_L,A_H)),
// (w1,w3) likewise from B.

#define Bb 4
#define Cc 64
#define HWs 4096
#define RLOG2E 1.44269504088896340736f
#define DEFER_THR 6.0f

typedef _Float16 half8 __attribute__((ext_vector_type(8)));
typedef _Float16 half4 __attribute__((ext_vector_type(4)));
typedef float floatx4 __attribute__((ext_vector_type(4)));
typedef unsigned uint2v __attribute__((ext_vector_type(2)));

// ---------------- prep: content copy + Vt convert + Kt transpose ----------------
__global__ __launch_bounds__(256) void prep_k(const float* __restrict__ content,
                                              const float* __restrict__ Fs,
                                              const float* __restrict__ Fst,
                                              float* __restrict__ out,
                                              _Float16* __restrict__ Kt,
                                              _Float16* __restrict__ Vt) {
    const int bid = blockIdx.x;
    const int t = threadIdx.x;
    if (bid < 1024) {
        // content copy (float4) + V f16 convert (same linear layout)
        int i4 = bid * 256 + t;                       // 0..262143
        const float4* c4 = (const float4*)content;
        const float4* v4 = (const float4*)Fst;
        float4* o4 = (float4*)out;
        int b = i4 >> 16, rem = i4 & 65535;
        o4[(size_t)b * 131072 + rem] = c4[i4];        // out batch stride 2*64*4096 f32
        float4 v = v4[i4];
        half4 h;
        h[0] = (_Float16)v.x; h[1] = (_Float16)v.y;
        h[2] = (_Float16)v.z; h[3] = (_Float16)v.w;
        *(half4*)(Vt + (size_t)i4 * 4) = h;
    } else {
        // transpose+convert one 16hw x 64c tile of Fs -> Kt[b][k][c]
        __shared__ _Float16 T[16][72];
        int e = bid - 1024;                           // 0..1023
        int b = e >> 8;
        int hw0 = (e & 255) * 16;
        const float* sb = Fs + (size_t)b * Cc * HWs;
        {
            int c = t >> 2, x4 = (t & 3) * 4;         // 256 float4 = whole tile
            float4 v = *(const float4*)(sb + (size_t)c * HWs + hw0 + x4);
            T[x4 + 0][c] = (_Float16)v.x;
            T[x4 + 1][c] = (_Float16)v.y;
            T[x4 + 2][c] = (_Float16)v.z;
            T[x4 + 3][c] = (_Float16)v.w;
        }
        __syncthreads();
        if (t < 128) {
            int row = t >> 3, g = t & 7;
            _Float16* db = Kt + (size_t)b * HWs * Cc;
            *(half8*)(db + (size_t)(hw0 + row) * Cc + g * 8) = *(half8*)&T[row][g * 8];
        }
    }
}

// ---------------- attn: flash, counted-vmcnt 3-buffer pipeline ----------------
template <int NS>
__global__ __launch_bounds__(256, 3) void attn_k(const float* __restrict__ Fc,
                                                 const _Float16* __restrict__ Kt,
                                                 const _Float16* __restrict__ Vt,
                                                 _Float16* __restrict__ Opart,
                                                 float2* __restrict__ ml) {
    constexpr int TPS = 64 / NS;                  // k-tiles per split
    const int tid  = threadIdx.x;                 // 0..255
    const int w    = tid >> 6;                    // wave 0..3
    const int lane = tid & 63;
    const int quad = lane >> 4;
    const int l15  = lane & 15;
    // block: [split][b][qgroup]
    const int qg = blockIdx.x & 31;
    const int b  = (blockIdx.x >> 5) & 3;
    const int s  = blockIdx.x >> 7;
    const int k0base = s * TPS * 64;
    const int qA = qg * 128 + w * 32 + l15;       // group 0 q-row
    const int qB = qA + 16;                       // group 1 q-row

    // xor-swizzled tiles: 16B chunk j of row r stored at chunk j^(r&7)
    __shared__ _Float16 Kl[3][64 * 64];
    __shared__ _Float16 Vl[3][64 * 64];

    const float*    Fcb = Fc + (size_t)b * Cc * HWs;
    const _Float16* Kb  = Kt + (size_t)b * HWs * Cc;
    const _Float16* Vb  = Vt + (size_t)b * Cc * HWs;

    // direct global->LDS staging. lane = lrow*8+lj writes LDS [row][chunk lj]
    // (linear, base+lane*16); source points at global chunk lj^lrow -> data
    // lands xor-swizzled. Rows of Kt (64c) and Vt (hw-contig) are both 128B.
    const int lrow = lane >> 3;                   // 0..7
    const int lj   = lane & 7;
    const int lsw8 = (lj ^ lrow) * 8;             // swizzled source chunk (halfs)
    const int r0   = w * 16;                      // this wave's 16-row slice

    auto stage = [&](int kt, int p) {             // 4 global_load_lds per lane
        const int kk0 = k0base + kt * 64;
        #pragma unroll
        for (int c = 0; c < 2; ++c) {
            const int r = r0 + c * 8 + lrow;
            __builtin_amdgcn_global_load_lds(
                (const __attribute__((address_space(1))) void*)(Kb + (size_t)(kk0 + r) * 64 + lsw8),
                (__attribute__((address_space(3))) void*)&Kl[p][(r0 + c * 8) * 64],
                16, 0, 0);
            __builtin_amdgcn_global_load_lds(
                (const __attribute__((address_space(1))) void*)(Vb + (size_t)r * HWs + kk0 + lsw8),
                (__attribute__((address_space(3))) void*)&Vl[p][(r0 + c * 8) * 64],
                16, 0, 0);
        }
    };

    // Q B-frags from fp32 Fc, pre-scaled by log2e (one-time strided loads)
    half8 qf[2][2];
    #pragma unroll
    for (int j = 0; j < 8; ++j) {
        qf[0][0][j] = (_Float16)(Fcb[(size_t)(quad * 8 + j) * HWs + qA] * RLOG2E);
        qf[0][1][j] = (_Float16)(Fcb[(size_t)(32 + quad * 8 + j) * HWs + qA] * RLOG2E);
        qf[1][0][j] = (_Float16)(Fcb[(size_t)(quad * 8 + j) * HWs + qB] * RLOG2E);
        qf[1][1][j] = (_Float16)(Fcb[(size_t)(32 + quad * 8 + j) * HWs + qB] * RLOG2E);
    }

    floatx4 acc[2][4];
    #pragma unroll
    for (int g = 0; g < 2; ++g)
        #pragma unroll
        for (int m = 0; m < 4; ++m) acc[g][m] = (floatx4)(0.0f);
    float m_run[2] = {-INFINITY, -INFINITY};
    float lsum[2] = {0.0f, 0.0f};

    // keep manual vmcnt bookkeeping exact: Q loads strictly before stages
    asm volatile("" ::: "memory");
    stage(0, 0);
    stage(1, 1);

    const int swl = (l15 & 7);
    #pragma unroll
    for (int kt = 0; kt < TPS; ++kt) {
        const int p = kt % 3;
        // wait for stage(kt): everything but the newest stage (kt+1, 4 loads)
        if (kt + 1 < TPS) asm volatile("s_waitcnt vmcnt(4)" ::: "memory");
        else              asm volatile("s_waitcnt vmcnt(0)" ::: "memory");
        __builtin_amdgcn_s_barrier();             // all waves: kt landed, kt-1 reads done
        __builtin_amdgcn_sched_barrier(0);
        if (kt + 2 < TPS) stage(kt + 2, (kt + 2) % 3);  // 2 tile-phases to land

        // S^T = K . Q  (per-m ka liveness: 8 regs)
        floatx4 sv[2][4];
        __builtin_amdgcn_s_setprio(1);
        #pragma unroll
        for (int m = 0; m < 4; ++m) {
            const half8 ka0 = *(const half8*)&Kl[p][(m * 16 + l15) * 64 + ((quad ^ swl) * 8)];
            const half8 ka1 = *(const half8*)&Kl[p][(m * 16 + l15) * 64 + (((4 + quad) ^ swl) * 8)];
            sv[0][m] = __builtin_amdgcn_mfma_f32_16x16x32_f16(ka0, qf[0][0], (floatx4)(0.0f), 0, 0, 0);
            sv[0][m] = __builtin_amdgcn_mfma_f32_16x16x32_f16(ka1, qf[0][1], sv[0][m], 0, 0, 0);
            sv[1][m] = __builtin_amdgcn_mfma_f32_16x16x32_f16(ka0, qf[1][0], (floatx4)(0.0f), 0, 0, 0);
            sv[1][m] = __builtin_amdgcn_mfma_f32_16x16x32_f16(ka1, qf[1][1], sv[1][m], 0, 0, 0);
        }
        __builtin_amdgcn_s_setprio(0);

        // online softmax per q-group (log2 domain), P -> B-frags in registers
        half8 pb[2][2];
        #pragma unroll
        for (int g = 0; g < 2; ++g) {
            // tree max (max3-fusable), short critical path
            float mm[4];
            #pragma unroll
            for (int m = 0; m < 4; ++m)
                mm[m] = fmaxf(fmaxf(sv[g][m][0], sv[g][m][1]),
                              fmaxf(sv[g][m][2], sv[g][m][3]));
            float mx = fmaxf(fmaxf(mm[0], mm[1]), fmaxf(mm[2], mm[3]));
            // cross-quad max reduce via permlane swaps (VALU pipe, not LDS)
            {
                unsigned mu = __float_as_uint(mx);
                uint2v t32 = __builtin_amdgcn_permlane32_swap(mu, mu, false, false);
                mx = fmaxf(__uint_as_float(t32[0]), __uint_as_float(t32[1]));
                mu = __float_as_uint(mx);
                uint2v t16 = __builtin_amdgcn_permlane16_swap(mu, mu, false, false);
                mx = fmaxf(__uint_as_float(t16[0]), __uint_as_float(t16[1]));
            }
            // defer-max: only rescale when some lane grew past THR (P <= 2^THR = 64)
            if (!__all(mx - m_run[g] <= DEFER_THR)) {
                float m_new = fmaxf(m_run[g], mx);
                float alpha = exp2f(m_run[g] - m_new);   // 0 on first tile
                m_run[g] = m_new;
                #pragma unroll
                for (int m = 0; m < 4; ++m) acc[g][m] *= alpha;
                lsum[g] *= alpha;
            }
            const float mb = m_run[g];
            unsigned Ap[4], Bp[4];
            #pragma unroll
            for (int m = 0; m < 4; ++m) {
                float e0 = exp2f(sv[g][m][0] - mb);
                float e1 = exp2f(sv[g][m][1] - mb);
                float e2 = exp2f(sv[g][m][2] - mb);
                float e3 = exp2f(sv[g][m][3] - mb);
                lsum[g] += (e0 + e1) + (e2 + e3);
                Ap[m] = __builtin_bit_cast(unsigned, __builtin_amdgcn_cvt_pkrtz(e0, e1));
                Bp[m] = __builtin_bit_cast(unsigned, __builtin_amdgcn_cvt_pkrtz(e2, e3));
            }
            // D-layout -> B-layout across quads: 2 swaps per word-pair
            unsigned pw[2][4];
            { uint2v a = __builtin_amdgcn_permlane32_swap(Ap[0], Ap[1], false, false);
              uint2v u = __builtin_amdgcn_permlane16_swap(a[0], a[1], false, false);
              pw[0][0] = u[0]; pw[0][2] = u[1]; }
            { uint2v a = __builtin_amdgcn_permlane32_swap(Bp[0], Bp[1], false, false);
              uint2v u = __builtin_amdgcn_permlane16_swap(a[0], a[1], false, false);
              pw[0][1] = u[0]; pw[0][3] = u[1]; }
            { uint2v a = __builtin_amdgcn_permlane32_swap(Ap[2], Ap[3], false, false);
              uint2v u = __builtin_amdgcn_permlane16_swap(a[0], a[1], false, false);
              pw[1][0] = u[0]; pw[1][2] = u[1]; }
            { uint2v a = __builtin_amdgcn_permlane32_swap(Bp[2], Bp[3], false, false);
              uint2v u = __builtin_amdgcn_permlane16_swap(a[0], a[1], false, false);
              pw[1][1] = u[0]; pw[1][3] = u[1]; }
            #pragma unroll
            for (int ks = 0; ks < 2; ++ks) {
                union { unsigned u4[4]; half8 h; } z;
                z.u4[0] = pw[ks][0]; z.u4[1] = pw[ks][1];
                z.u4[2] = pw[ks][2]; z.u4[3] = pw[ks][3];
                pb[g][ks] = z.h;
            }
        }

        // O^T update: D[m=c][n=q]  (per-m va liveness: 8 regs)
        __builtin_amdgcn_s_setprio(1);
        #pragma unroll
        for (int m = 0; m < 4; ++m) {
            const half8 va0 = *(const half8*)&Vl[p][(m * 16 + l15) * 64 + ((quad ^ swl) * 8)];
            const half8 va1 = *(const half8*)&Vl[p][(m * 16 + l15) * 64 + (((4 + quad) ^ swl) * 8)];
            acc[0][m] = __builtin_amdgcn_mfma_f32_16x16x32_f16(va0, pb[0][0], acc[0][m], 0, 0, 0);
            acc[0][m] = __builtin_amdgcn_mfma_f32_16x16x32_f16(va1, pb[0][1], acc[0][m], 0, 0, 0);
            acc[1][m] = __builtin_amdgcn_mfma_f32_16x16x32_f16(va0, pb[1][0], acc[1][m], 0, 0, 0);
            acc[1][m] = __builtin_amdgcn_mfma_f32_16x16x32_f16(va1, pb[1][1], acc[1][m], 0, 0, 0);
        }
        __builtin_amdgcn_s_setprio(0);
        // no trailing barrier: next iteration's vmcnt+barrier covers both
        // "stage landed" and "everyone done reading" hazards.
    }

    // reduce row-sums across quads (once), write partials (f16) + (M,l)
    _Float16* op = Opart + ((size_t)(s * Bb + b) * Cc) * HWs;
    #pragma unroll
    for (int g = 0; g < 2; ++g) {
        lsum[g] += __shfl_xor(lsum[g], 16);
        lsum[g] += __shfl_xor(lsum[g], 32);
        int q = (g == 0) ? qA : qB;
        #pragma unroll
        for (int m = 0; m < 4; ++m)
            #pragma unroll
            for (int r = 0; r < 4; ++r) {
                int c = m * 16 + quad * 4 + r;
                op[(size_t)c * HWs + q] = (_Float16)acc[g][m][r];
            }
        if (quad == 0)
            ml[((size_t)b * HWs + q) * NS + s] = make_float2(m_run[g], lsum[g]);
    }
}

// ---------------- combine: merge splits (exp2 domain) ----------------
template <int NS>
__global__ __launch_bounds__(256) void combine_k(const _Float16* __restrict__ Opart,
                                                 const float2* __restrict__ ml,
                                                 float* __restrict__ out) {
    int idx = blockIdx.x * 256 + threadIdx.x;     // over 4*64*4096 = 1M
    int q = idx & 4095;
    int c = (idx >> 12) & 63;
    int b = idx >> 18;
    const float2* mlp = ml + ((size_t)b * HWs + q) * NS;
    float2 mls[NS];
    #pragma unroll
    for (int s = 0; s < NS; ++s) mls[s] = mlp[s];
    float M = -INFINITY;
    #pragma unroll
    for (int s = 0; s < NS; ++s) M = fmaxf(M, mls[s].x);
    float l = 0.0f, o = 0.0f;
    #pragma unroll
    for (int s = 0; s < NS; ++s) {
        float wgt = exp2f(mls[s].x - M);
        l += wgt * mls[s].y;
        o += wgt * (float)Opart[(((size_t)s * Bb + b) * Cc + c) * HWs + q];
    }
    out[((size_t)b * 2 * Cc + Cc + c) * HWs + q] = o / l;
}

extern "C" void kernel_launch(void* const* d_in, const int* in_sizes, int n_in,
                              void* d_out, int out_size, void* d_ws, size_t ws_size,
                              hipStream_t stream) {
    const float* content   = (const float*)d_in[0];
    const float* content_s = (const float*)d_in[1];
    const float* style     = (const float*)d_in[2];
    float* out = (float*)d_out;

    _Float16* Kt = (_Float16*)d_ws;                           // [4][4096][64] f16  (2 MB)
    _Float16* Vt = Kt + (size_t)Bb * HWs * Cc;                // [4][64][4096] f16  (2 MB)
    _Float16* Opart = Vt + (size_t)Bb * Cc * HWs;             // [NS][4][64][4096] f16

    const size_t base = (size_t)2 * Bb * HWs * Cc * sizeof(_Float16);
    const size_t need8 = base + (size_t)8 * Bb * Cc * HWs * sizeof(_Float16)
                              + (size_t)Bb * HWs * 8 * sizeof(float2);
    const int ns = (ws_size >= need8) ? 8 : 4;
    float2* ml = (float2*)(Opart + (size_t)ns * Bb * Cc * HWs);

    prep_k<<<dim3(2048), dim3(256), 0, stream>>>(content, content_s, style, out, Kt, Vt);
    if (ns == 8) {
        attn_k<8><<<dim3(8 * Bb * 32), dim3(256), 0, stream>>>(content, Kt, Vt, Opart, ml);
        combine_k<8><<<dim3(4096), dim3(256), 0, stream>>>(Opart, ml, out);
    } else {
        attn_k<4><<<dim3(4 * Bb * 32), dim3(256), 0, stream>>>(content, Kt, Vt, Opart, ml);
        combine_k<4><<<dim3(4096), dim3(256), 0, stream>>>(Opart, ml, out);
    }
}

// Round 5
// 112.310 us; speedup vs baseline: 1.0100x; 1.0100x over previous
//
#include <hip/hip_runtime.h>
#include <math.h>

// SANet attention: MFMA flash, gload_lds-staged K/V (source-preswizzled),
// split-lead 3-ring K/V + counted vmcnt, T15 intra-wave double pipeline:
// S(kt+1) MFMA overlaps softmax(kt) VALU. b=4, c=64, HW=4096, fp32 in/out.
//
// R9 post-mortem: 4 structural variants flat at attn~40-44us. R0 counters:
// MFMA 8.8us + VALU 22us + LDS ~14us = 44.8 = SUM -> intra-wave serial chain
// (ds_read->S->softmax->PV->barrier), occupancy can't fix it (lockstep waves).
// R10: per iter { waits; barrier; stageK(kt+3); stageV(kt+2);
//                 S(kt+1)->sv_next; softmax(kt) on sv_cur; PV(kt) }
// S(kt+1) is independent of softmax(kt) -> matrix pipe runs under the VALU
// burst. K ring read at iter kt-1 lead, V at kt -> K staged +3, V +2.
// vmcnt: need {K(kt+1),V(kt)}; issued-after = K(kt+2)+V(kt+1) = 4 loads
// (2/stage-call); tail 2/0. One barrier per iter; never vmcnt(0) mid-loop.
// Max-reduce hoisted into rare rescale branch (__all over per-lane maxes is
// an equivalent trigger). Ping-pong svA/svB via ref-taking lambda (rule #20).
//
// mfma_f32_16x16x32_f16: A[m=lane&15][k=quad*8+j], B[k=quad*8+j][n=lane&15],
// D[m=quad*4+reg][n=lane&15]  (quad = lane>>4).
// S-mfma computes S^T tile (m=k_key, n=q); PV computes O^T (m=c, n=q).
// P redistribution (verified R7): A_m=pk(sv[m][0],sv[m][1]),
// B_m=pk(sv[m][2],sv[m][3]); (w0,w2)=pl16swap(pl32swap(A_L,A_H)); (w1,w3) from B.

#define Bb 4
#define Cc 64
#define HWs 4096
#define RLOG2E 1.44269504088896340736f
#define DEFER_THR 6.0f

typedef _Float16 half8 __attribute__((ext_vector_type(8)));
typedef _Float16 half4 __attribute__((ext_vector_type(4)));
typedef float floatx4 __attribute__((ext_vector_type(4)));
typedef unsigned uint2v __attribute__((ext_vector_type(2)));

#define GAS __attribute__((address_space(1)))
#define LAS __attribute__((address_space(3)))

// ---------------- prep: content copy + Vt convert + Kt transpose ----------------
__global__ __launch_bounds__(256) void prep_k(const float* __restrict__ content,
                                              const float* __restrict__ Fs,
                                              const float* __restrict__ Fst,
                                              float* __restrict__ out,
                                              _Float16* __restrict__ Kt,
                                              _Float16* __restrict__ Vt) {
    const int bid = blockIdx.x;
    const int t = threadIdx.x;
    if (bid < 1024) {
        // content copy (float4) + V f16 convert (same linear layout)
        int i4 = bid * 256 + t;                       // 0..262143
        const float4* c4 = (const float4*)content;
        const float4* v4 = (const float4*)Fst;
        float4* o4 = (float4*)out;
        int b = i4 >> 16, rem = i4 & 65535;
        o4[(size_t)b * 131072 + rem] = c4[i4];        // out batch stride 2*64*4096 f32
        float4 v = v4[i4];
        half4 h;
        h[0] = (_Float16)v.x; h[1] = (_Float16)v.y;
        h[2] = (_Float16)v.z; h[3] = (_Float16)v.w;
        *(half4*)(Vt + (size_t)i4 * 4) = h;
    } else {
        // transpose+convert one 16hw x 64c tile of Fs -> Kt[b][k][c]
        __shared__ _Float16 T[16][72];
        int e = bid - 1024;                           // 0..1023
        int b = e >> 8;
        int hw0 = (e & 255) * 16;
        const float* sb = Fs + (size_t)b * Cc * HWs;
        {
            int c = t >> 2, x4 = (t & 3) * 4;         // 256 float4 = whole tile
            float4 v = *(const float4*)(sb + (size_t)c * HWs + hw0 + x4);
            T[x4 + 0][c] = (_Float16)v.x;
            T[x4 + 1][c] = (_Float16)v.y;
            T[x4 + 2][c] = (_Float16)v.z;
            T[x4 + 3][c] = (_Float16)v.w;
        }
        __syncthreads();
        if (t < 128) {
            int row = t >> 3, g = t & 7;
            _Float16* db = Kt + (size_t)b * HWs * Cc;
            *(half8*)(db + (size_t)(hw0 + row) * Cc + g * 8) = *(half8*)&T[row][g * 8];
        }
    }
}

// ---------------- attn: flash, double-pipelined tiles ----------------
template <int NS>
__global__ __launch_bounds__(256, 3) void attn_k(const float* __restrict__ Fc,
                                                 const _Float16* __restrict__ Kt,
                                                 const _Float16* __restrict__ Vt,
                                                 _Float16* __restrict__ Opart,
                                                 float2* __restrict__ ml) {
    constexpr int TPS = 64 / NS;                  // k-tiles per split (even)
    const int tid  = threadIdx.x;                 // 0..255
    const int w    = tid >> 6;                    // wave 0..3
    const int lane = tid & 63;
    const int quad = lane >> 4;
    const int l15  = lane & 15;
    // block: [split][b][qgroup]
    const int qg = blockIdx.x & 31;
    const int b  = (blockIdx.x >> 5) & 3;
    const int s  = blockIdx.x >> 7;
    const int k0base = s * TPS * 64;
    const int qA = qg * 128 + w * 32 + l15;       // group 0 q-row
    const int qB = qA + 16;                       // group 1 q-row

    // xor-swizzled tiles: 16B chunk j of row r stored at chunk j^(r&7)
    __shared__ _Float16 Kl[3][64 * 64];
    __shared__ _Float16 Vl[3][64 * 64];

    const float*    Fcb = Fc + (size_t)b * Cc * HWs;
    const _Float16* Kb  = Kt + (size_t)b * HWs * Cc;
    const _Float16* Vb  = Vt + (size_t)b * Cc * HWs;

    // gload_lds staging: lane lrow*8+lj writes LDS row (r0+c*8+lrow), chunk lj
    // (linear dest = wave base + lane*16B); source chunk lj^lrow -> swizzled.
    const int lrow = lane >> 3;                   // 0..7
    const int lj   = lane & 7;
    const int lsw8 = (lj ^ lrow) * 8;             // swizzled source chunk (halfs)
    const int r0   = w * 16;                      // wave's 16-row slice

    auto stageK = [&](int kt) {                   // 2 loads/lane
        const int kk0 = k0base + kt * 64;
        #pragma unroll
        for (int c = 0; c < 2; ++c) {
            const int r = r0 + c * 8 + lrow;
            __builtin_amdgcn_global_load_lds(
                (const GAS void*)(Kb + (size_t)(kk0 + r) * 64 + lsw8),
                (LAS void*)&Kl[kt % 3][(r0 + c * 8) * 64], 16, 0, 0);
        }
    };
    auto stageV = [&](int kt) {                   // 2 loads/lane
        const int kk0 = k0base + kt * 64;
        #pragma unroll
        for (int c = 0; c < 2; ++c) {
            const int r = r0 + c * 8 + lrow;
            __builtin_amdgcn_global_load_lds(
                (const GAS void*)(Vb + (size_t)r * HWs + kk0 + lsw8),
                (LAS void*)&Vl[kt % 3][(r0 + c * 8) * 64], 16, 0, 0);
        }
    };

    // Q B-frags from fp32 Fc, pre-scaled by log2e (one-time strided loads)
    half8 qf[2][2];
    #pragma unroll
    for (int j = 0; j < 8; ++j) {
        qf[0][0][j] = (_Float16)(Fcb[(size_t)(quad * 8 + j) * HWs + qA] * RLOG2E);
        qf[0][1][j] = (_Float16)(Fcb[(size_t)(32 + quad * 8 + j) * HWs + qA] * RLOG2E);
        qf[1][0][j] = (_Float16)(Fcb[(size_t)(quad * 8 + j) * HWs + qB] * RLOG2E);
        qf[1][1][j] = (_Float16)(Fcb[(size_t)(32 + quad * 8 + j) * HWs + qB] * RLOG2E);
    }

    floatx4 acc[2][4];
    #pragma unroll
    for (int g = 0; g < 2; ++g)
        #pragma unroll
        for (int m = 0; m < 4; ++m) acc[g][m] = (floatx4)(0.0f);
    float m_run[2] = {-INFINITY, -INFINITY};
    float lsum[2] = {0.0f, 0.0f};

    const int swl = l15 & 7;
    const int o0 = (quad ^ swl) * 8;              // ka0/va0 swizzled chunk
    const int o1 = ((4 + quad) ^ swl) * 8;        // ka1/va1

    // S^T(kt1) = K(kt1).Q  -> sv   (matrix pipe; independent of softmax(kt))
    auto s_mfma = [&](int kt1, floatx4 (&sv)[2][4]) {
        const _Float16* K = &Kl[kt1 % 3][0];
        __builtin_amdgcn_s_setprio(1);
        #pragma unroll
        for (int m = 0; m < 4; ++m) {
            const half8 ka0 = *(const half8*)(K + (m * 16 + l15) * 64 + o0);
            const half8 ka1 = *(const half8*)(K + (m * 16 + l15) * 64 + o1);
            sv[0][m] = __builtin_amdgcn_mfma_f32_16x16x32_f16(ka0, qf[0][0], (floatx4)(0.0f), 0, 0, 0);
            sv[0][m] = __builtin_amdgcn_mfma_f32_16x16x32_f16(ka1, qf[0][1], sv[0][m], 0, 0, 0);
            sv[1][m] = __builtin_amdgcn_mfma_f32_16x16x32_f16(ka0, qf[1][0], (floatx4)(0.0f), 0, 0, 0);
            sv[1][m] = __builtin_amdgcn_mfma_f32_16x16x32_f16(ka1, qf[1][1], sv[1][m], 0, 0, 0);
        }
        __builtin_amdgcn_s_setprio(0);
    };

    // softmax(kt) on sv + PV(kt)
    auto sm_pv = [&](int kt, floatx4 (&sv)[2][4]) {
        half8 pb[2][2];
        #pragma unroll
        for (int g = 0; g < 2; ++g) {
            float mm0 = fmaxf(fmaxf(sv[g][0][0], sv[g][0][1]), fmaxf(sv[g][0][2], sv[g][0][3]));
            float mm1 = fmaxf(fmaxf(sv[g][1][0], sv[g][1][1]), fmaxf(sv[g][1][2], sv[g][1][3]));
            float mm2 = fmaxf(fmaxf(sv[g][2][0], sv[g][2][1]), fmaxf(sv[g][2][2], sv[g][2][3]));
            float mm3 = fmaxf(fmaxf(sv[g][3][0], sv[g][3][1]), fmaxf(sv[g][3][2], sv[g][3][3]));
            float mx = fmaxf(fmaxf(mm0, mm1), fmaxf(mm2, mm3));
            // defer-max: per-lane check is an equivalent wave trigger (__all)
            if (!__all(mx - m_run[g] <= DEFER_THR)) {
                unsigned mu = __float_as_uint(mx);
                uint2v t32 = __builtin_amdgcn_permlane32_swap(mu, mu, false, false);
                float wmx = fmaxf(__uint_as_float(t32[0]), __uint_as_float(t32[1]));
                mu = __float_as_uint(wmx);
                uint2v t16 = __builtin_amdgcn_permlane16_swap(mu, mu, false, false);
                wmx = fmaxf(__uint_as_float(t16[0]), __uint_as_float(t16[1]));
                float m_new = fmaxf(m_run[g], wmx);   // wave-uniform
                float alpha = exp2f(m_run[g] - m_new);// 0 on first tile
                m_run[g] = m_new;
                #pragma unroll
                for (int m = 0; m < 4; ++m) acc[g][m] *= alpha;
                lsum[g] *= alpha;
            }
            const float mb = m_run[g];
            unsigned Ap[4], Bp[4];
            #pragma unroll
            for (int m = 0; m < 4; ++m) {
                float e0 = exp2f(sv[g][m][0] - mb);
                float e1 = exp2f(sv[g][m][1] - mb);
                float e2 = exp2f(sv[g][m][2] - mb);
                float e3 = exp2f(sv[g][m][3] - mb);
                lsum[g] += (e0 + e1) + (e2 + e3);
                Ap[m] = __builtin_bit_cast(unsigned, __builtin_amdgcn_cvt_pkrtz(e0, e1));
                Bp[m] = __builtin_bit_cast(unsigned, __builtin_amdgcn_cvt_pkrtz(e2, e3));
            }
            // D-layout -> B-layout across quads: 2 swaps per word-pair
            unsigned pw[2][4];
            { uint2v a = __builtin_amdgcn_permlane32_swap(Ap[0], Ap[1], false, false);
              uint2v u = __builtin_amdgcn_permlane16_swap(a[0], a[1], false, false);
              pw[0][0] = u[0]; pw[0][2] = u[1]; }
            { uint2v a = __builtin_amdgcn_permlane32_swap(Bp[0], Bp[1], false, false);
              uint2v u = __builtin_amdgcn_permlane16_swap(a[0], a[1], false, false);
              pw[0][1] = u[0]; pw[0][3] = u[1]; }
            { uint2v a = __builtin_amdgcn_permlane32_swap(Ap[2], Ap[3], false, false);
              uint2v u = __builtin_amdgcn_permlane16_swap(a[0], a[1], false, false);
              pw[1][0] = u[0]; pw[1][2] = u[1]; }
            { uint2v a = __builtin_amdgcn_permlane32_swap(Bp[2], Bp[3], false, false);
              uint2v u = __builtin_amdgcn_permlane16_swap(a[0], a[1], false, false);
              pw[1][1] = u[0]; pw[1][3] = u[1]; }
            #pragma unroll
            for (int ks = 0; ks < 2; ++ks) {
                union { unsigned u4[4]; half8 h; } z;
                z.u4[0] = pw[ks][0]; z.u4[1] = pw[ks][1];
                z.u4[2] = pw[ks][2]; z.u4[3] = pw[ks][3];
                pb[g][ks] = z.h;
            }
        }
        const _Float16* V = &Vl[kt % 3][0];
        __builtin_amdgcn_s_setprio(1);
        #pragma unroll
        for (int m = 0; m < 4; ++m) {
            const half8 va0 = *(const half8*)(V + (m * 16 + l15) * 64 + o0);
            const half8 va1 = *(const half8*)(V + (m * 16 + l15) * 64 + o1);
            acc[0][m] = __builtin_amdgcn_mfma_f32_16x16x32_f16(va0, pb[0][0], acc[0][m], 0, 0, 0);
            acc[0][m] = __builtin_amdgcn_mfma_f32_16x16x32_f16(va1, pb[0][1], acc[0][m], 0, 0, 0);
            acc[1][m] = __builtin_amdgcn_mfma_f32_16x16x32_f16(va0, pb[1][0], acc[1][m], 0, 0, 0);
            acc[1][m] = __builtin_amdgcn_mfma_f32_16x16x32_f16(va1, pb[1][1], acc[1][m], 0, 0, 0);
        }
        __builtin_amdgcn_s_setprio(0);
    };

    // one pipeline iteration. Hazards (all barrier-or-vmcnt covered):
    //  stageK(kt+3)->Kl[kt%3]: K(kt) read iter kt-1, pre-barrier(kt).
    //  stageV(kt+2)->Vl[(kt+2)%3]: V(kt-1) read iter kt-1, pre-barrier(kt).
    //  needs: K(kt+1) (staged kt-2), V(kt) (staged kt-2) -> 2 phases in flight.
    auto iter = [&](int kt, floatx4 (&cur)[2][4], floatx4 (&nxt)[2][4]) {
        if (kt + 2 < TPS)      asm volatile("s_waitcnt vmcnt(4)" ::: "memory");
        else if (kt + 1 < TPS) asm volatile("s_waitcnt vmcnt(2)" ::: "memory");
        else                   asm volatile("s_waitcnt vmcnt(0)" ::: "memory");
        __builtin_amdgcn_s_barrier();
        __builtin_amdgcn_sched_barrier(0);
        if (kt + 3 < TPS) stageK(kt + 3);
        if (kt + 2 < TPS) stageV(kt + 2);
        if (kt + 1 < TPS) s_mfma(kt + 1, nxt);    // matrix pipe, overlaps:
        sm_pv(kt, cur);                           // VALU softmax + PV
    };

    // prologue: issue order fixed by fence; K leads V by one tile.
    asm volatile("" ::: "memory");                // Q loads strictly before stages
    stageK(0); stageK(1); stageV(0); stageK(2); stageV(1);   // 10 loads
    asm volatile("s_waitcnt vmcnt(4)" ::: "memory");          // K0,K1,V0 landed
    __builtin_amdgcn_s_barrier();
    __builtin_amdgcn_sched_barrier(0);

    floatx4 svA[2][4], svB[2][4];
    s_mfma(0, svA);

    #pragma unroll
    for (int kt = 0; kt < TPS; kt += 2) {
        iter(kt, svA, svB);
        iter(kt + 1, svB, svA);
    }

    // reduce row-sums across quads (once), write partials (f16) + (M,l)
    _Float16* op = Opart + ((size_t)(s * Bb + b) * Cc) * HWs;
    #pragma unroll
    for (int g = 0; g < 2; ++g) {
        lsum[g] += __shfl_xor(lsum[g], 16);
        lsum[g] += __shfl_xor(lsum[g], 32);
        int q = (g == 0) ? qA : qB;
        #pragma unroll
        for (int m = 0; m < 4; ++m)
            #pragma unroll
            for (int r = 0; r < 4; ++r) {
                int c = m * 16 + quad * 4 + r;
                op[(size_t)c * HWs + q] = (_Float16)acc[g][m][r];
            }
        if (quad == 0)
            ml[((size_t)b * HWs + q) * NS + s] = make_float2(m_run[g], lsum[g]);
    }
}

// ---------------- combine: merge splits (exp2 domain) ----------------
template <int NS>
__global__ __launch_bounds__(256) void combine_k(const _Float16* __restrict__ Opart,
                                                 const float2* __restrict__ ml,
                                                 float* __restrict__ out) {
    int idx = blockIdx.x * 256 + threadIdx.x;     // over 4*64*4096 = 1M
    int q = idx & 4095;
    int c = (idx >> 12) & 63;
    int b = idx >> 18;
    const float2* mlp = ml + ((size_t)b * HWs + q) * NS;
    float2 mls[NS];
    #pragma unroll
    for (int s = 0; s < NS; ++s) mls[s] = mlp[s];
    float M = -INFINITY;
    #pragma unroll
    for (int s = 0; s < NS; ++s) M = fmaxf(M, mls[s].x);
    float l = 0.0f, o = 0.0f;
    #pragma unroll
    for (int s = 0; s < NS; ++s) {
        float wgt = exp2f(mls[s].x - M);
        l += wgt * mls[s].y;
        o += wgt * (float)Opart[(((size_t)s * Bb + b) * Cc + c) * HWs + q];
    }
    out[((size_t)b * 2 * Cc + Cc + c) * HWs + q] = o / l;
}

extern "C" void kernel_launch(void* const* d_in, const int* in_sizes, int n_in,
                              void* d_out, int out_size, void* d_ws, size_t ws_size,
                              hipStream_t stream) {
    const float* content   = (const float*)d_in[0];
    const float* content_s = (const float*)d_in[1];
    const float* style     = (const float*)d_in[2];
    float* out = (float*)d_out;

    _Float16* Kt = (_Float16*)d_ws;                           // [4][4096][64] f16  (2 MB)
    _Float16* Vt = Kt + (size_t)Bb * HWs * Cc;                // [4][64][4096] f16  (2 MB)
    _Float16* Opart = Vt + (size_t)Bb * Cc * HWs;             // [NS][4][64][4096] f16

    const size_t base = (size_t)2 * Bb * HWs * Cc * sizeof(_Float16);
    const size_t need8 = base + (size_t)8 * Bb * Cc * HWs * sizeof(_Float16)
                              + (size_t)Bb * HWs * 8 * sizeof(float2);
    const int ns = (ws_size >= need8) ? 8 : 4;
    float2* ml = (float2*)(Opart + (size_t)ns * Bb * Cc * HWs);

    prep_k<<<dim3(2048), dim3(256), 0, stream>>>(content, content_s, style, out, Kt, Vt);
    if (ns == 8) {
        attn_k<8><<<dim3(8 * Bb * 32), dim3(256), 0, stream>>>(content, Kt, Vt, Opart, ml);
        combine_k<8><<<dim3(4096), dim3(256), 0, stream>>>(Opart, ml, out);
    } else {
        attn_k<4><<<dim3(4 * Bb * 32), dim3(256), 0, stream>>>(content, Kt, Vt, Opart, ml);
        combine_k<4><<<dim3(4096), dim3(256), 0, stream>>>(Opart, ml, out);
    }
}